// Round 5
// baseline (850.749 us; speedup 1.0000x reference)
//
#include <hip/hip_runtime.h>
#include <math.h>

#define H 4096
#define INP 512
#define OUTN 64
#define H4 1024              // float4 per row
#define NBLK 1024            // fused grid: must equal co-resident capacity (4/CU x 256)
#define SPLITS 256           // NBLK/4 col-tiles
#define ROWS 16              // H / SPLITS

typedef float v4f __attribute__((ext_vector_type(4)));

// Software grid barrier. Safe because NBLK=1024 blocks of 256 thr at
// __launch_bounds__(256,4) (VGPR<=128, tiny LDS) are guaranteed co-resident
// (4 blocks/CU x 256 CUs). Device-scope atomics + agent fences handle
// cross-XCD visibility.
__device__ __forceinline__ void grid_barrier(unsigned* ctr, unsigned target) {
    __threadfence();                 // release: this thread's global stores
    __syncthreads();                 // whole block has fenced
    if (threadIdx.x == 0) {
        atomicAdd(ctr, 1u);
        while (atomicAdd(ctr, 0u) < target)
            __builtin_amdgcn_s_sleep(2);
    }
    __syncthreads();
    __threadfence();                 // acquire
}

__global__ __launch_bounds__(256, 4) void fused_rnn(
    const float* __restrict__ inp,
    const float* __restrict__ hidden,
    const float* __restrict__ hebb,
    const float* __restrict__ W_i2h,
    const float* __restrict__ b_i2h,
    const float* __restrict__ w,
    const float* __restrict__ plas,
    const float* __restrict__ learn,
    const float* __restrict__ W_h2o,
    const float* __restrict__ b_h2o,
    float* __restrict__ out,
    float* __restrict__ x,
    float* __restrict__ hebb_out,
    float* __restrict__ partial,
    unsigned* __restrict__ ctr)
{
    const int tid  = threadIdx.x;
    const int bid  = blockIdx.x;
    const int s    = bid >> 2;                 // split 0..255
    const int col4 = (bid & 3) * 256 + tid;    // float4 col 0..1023
    const int i0   = s * ROWS;

    const float4* __restrict__ w4 = (const float4*)w;
    const float4* __restrict__ p4 = (const float4*)plas;
    const float4* __restrict__ h4 = (const float4*)hebb;

    // ---- phase A: split-K partial matvec; hebb stays in registers ----------
    float4 hb[ROWS];
    float4 acc = make_float4(0.f, 0.f, 0.f, 0.f);
#pragma unroll
    for (int r = 0; r < ROWS; ++r) {
        const int i = i0 + r;
        const float hv = hidden[i];
        const size_t idx = (size_t)i * H4 + col4;
        const float4 wv = w4[idx];
        const float4 pv = p4[idx];
        hb[r] = h4[idx];
        acc.x += hv * (wv.x + pv.x * hb[r].x);
        acc.y += hv * (wv.y + pv.y * hb[r].y);
        acc.z += hv * (wv.z + pv.z * hb[r].z);
        acc.w += hv * (wv.w + pv.w * hb[r].w);
    }
    ((float4*)partial)[(size_t)s * H4 + col4] = acc;

    grid_barrier(ctr + 0, NBLK);

    // ---- phase B: one wave per j finishes x[j] -----------------------------
    {
        const int lane = tid & 63;
        const int j = bid * 4 + (tid >> 6);    // 0..4095
        float sum = 0.f;
#pragma unroll
        for (int k = 0; k < 4; ++k)
            sum += partial[(size_t)(lane + 64 * k) * H + j];

        const float4* __restrict__ row4 = (const float4*)(W_i2h + (size_t)j * INP);
        const float4* __restrict__ in4  = (const float4*)inp;
#pragma unroll
        for (int k = 0; k < 2; ++k) {
            const float4 a = row4[lane + 64 * k];
            const float4 b = in4[lane + 64 * k];
            sum += a.x * b.x + a.y * b.y + a.z * b.z + a.w * b.w;
        }
#pragma unroll
        for (int off = 32; off > 0; off >>= 1)
            sum += __shfl_down(sum, off, 64);
        if (lane == 0) {
            const float pre = sum + b_i2h[j];
            x[j] = pre > 0.f ? pre : 0.f;
        }
    }

    grid_barrier(ctr + 1, NBLK);

    // ---- phase C: hebb update from registers (no hebb re-read) -------------
    {
        const float lr = learn[0];
        const float om = 1.f - lr;
        const float4 xv = ((const float4*)x)[col4];
        v4f* __restrict__ o4 = (v4f*)hebb_out;
#pragma unroll
        for (int r = 0; r < ROWS; ++r) {
            const int i = i0 + r;
            const float coef = lr * hidden[i];
            v4f o;
            o.x = om * hb[r].x + coef * xv.x;
            o.y = om * hb[r].y + coef * xv.y;
            o.z = om * hb[r].z + coef * xv.z;
            o.w = om * hb[r].w + coef * xv.w;
            __builtin_nontemporal_store(o, &o4[(size_t)i * H4 + col4]);
        }
    }

    // ---- phase D: output head (x complete since barrier 2) -----------------
    if (bid < OUTN) {
        const int o = bid;
        const float4* __restrict__ row4 = (const float4*)(W_h2o + (size_t)o * H);
        const float4* __restrict__ x4   = (const float4*)x;
        float sum = 0.f;
#pragma unroll
        for (int c = tid; c < H4; c += 256) {
            const float4 a = row4[c];
            const float4 b = x4[c];
            sum += a.x * b.x + a.y * b.y + a.z * b.z + a.w * b.w;
        }
#pragma unroll
        for (int off = 32; off > 0; off >>= 1)
            sum += __shfl_down(sum, off, 64);
        __shared__ float red[4];
        const int lane = tid & 63;
        if (lane == 0) red[tid >> 6] = sum;
        __syncthreads();
        if (tid == 0) {
            const float ssum = red[0] + red[1] + red[2] + red[3];
            out[o] = tanhf(ssum + b_h2o[o]);
        }
    }
}

// ======================= fallback path (proven R4 kernels) ==================
#define FSPLITS 1024
#define FROWS 4

__global__ __launch_bounds__(256) void k_partial_fb(
    const float* __restrict__ hidden, const float* __restrict__ w,
    const float* __restrict__ plas, const float* __restrict__ hebb,
    float* __restrict__ partial)
{
    const int col4 = blockIdx.x * 256 + threadIdx.x;
    const int i0   = blockIdx.y * FROWS;
    const float4* __restrict__ w4 = (const float4*)w;
    const float4* __restrict__ p4 = (const float4*)plas;
    const float4* __restrict__ h4 = (const float4*)hebb;
    float4 acc = make_float4(0.f, 0.f, 0.f, 0.f);
#pragma unroll
    for (int r = 0; r < FROWS; ++r) {
        const int i = i0 + r;
        const float hv = hidden[i];
        const size_t idx = (size_t)i * H4 + col4;
        const float4 wv = w4[idx];
        const float4 pv = p4[idx];
        const float4 hbv = h4[idx];
        acc.x += hv * (wv.x + pv.x * hbv.x);
        acc.y += hv * (wv.y + pv.y * hbv.y);
        acc.z += hv * (wv.z + pv.z * hbv.z);
        acc.w += hv * (wv.w + pv.w * hbv.w);
    }
    ((float4*)partial)[(size_t)blockIdx.y * H4 + col4] = acc;
}

__global__ __launch_bounds__(256) void k_finish_x_fb(
    const float* __restrict__ partial, const float* __restrict__ inp,
    const float* __restrict__ W_i2h, const float* __restrict__ b_i2h,
    float* __restrict__ x_out)
{
    const int t  = threadIdx.x;
    const int j0 = blockIdx.x * 16;
    const int jj = t & 15;
    const int sg = t >> 4;
    float sum = 0.f;
    for (int s = sg; s < FSPLITS; s += 16)
        sum += partial[(size_t)s * H + j0 + jj];
    __shared__ float red[16][17];
    red[sg][jj] = sum;
    __syncthreads();
    const int wave = t >> 6;
    const int lane = t & 63;
    const float4* __restrict__ in4 = (const float4*)inp;
#pragma unroll
    for (int q = 0; q < 4; ++q) {
        const int jj2 = wave * 4 + q;
        const int j = j0 + jj2;
        const float4* __restrict__ row4 = (const float4*)(W_i2h + (size_t)j * INP);
        float d = 0.f;
#pragma unroll
        for (int k = 0; k < 2; ++k) {
            const float4 a = row4[lane + 64 * k];
            const float4 b = in4[lane + 64 * k];
            d += a.x * b.x + a.y * b.y + a.z * b.z + a.w * b.w;
        }
#pragma unroll
        for (int off = 32; off > 0; off >>= 1)
            d += __shfl_down(d, off, 64);
        if (lane == 0) {
            float tot = d + b_i2h[j];
#pragma unroll
            for (int g = 0; g < 16; ++g) tot += red[g][jj2];
            x_out[j] = tot > 0.f ? tot : 0.f;
        }
    }
}

__global__ __launch_bounds__(256) void k_hebb_out_fb(
    const float* __restrict__ hebb, const float* __restrict__ hidden,
    const float* __restrict__ x, const float* __restrict__ learn,
    const float* __restrict__ W_h2o, const float* __restrict__ b_h2o,
    float* __restrict__ hebb_out, float* __restrict__ out)
{
    if (blockIdx.x < H) {
        const int i = blockIdx.x;
        const float lr = learn[0];
        const float om = 1.f - lr;
        const float coef = lr * hidden[i];
        const float4* __restrict__ hb4 = (const float4*)hebb;
        const float4* __restrict__ x4  = (const float4*)x;
        v4f* __restrict__ o4 = (v4f*)hebb_out;
        const size_t base = (size_t)i * H4;
#pragma unroll
        for (int c = threadIdx.x; c < H4; c += 256) {
            const float4 hv = hb4[base + c];
            const float4 xv = x4[c];
            v4f r;
            r.x = om * hv.x + coef * xv.x;
            r.y = om * hv.y + coef * xv.y;
            r.z = om * hv.z + coef * xv.z;
            r.w = om * hv.w + coef * xv.w;
            __builtin_nontemporal_store(r, &o4[base + c]);
        }
    } else {
        const int o = blockIdx.x - H;
        const float4* __restrict__ row4 = (const float4*)(W_h2o + (size_t)o * H);
        const float4* __restrict__ x4   = (const float4*)x;
        float sum = 0.f;
#pragma unroll
        for (int c = threadIdx.x; c < H4; c += 256) {
            const float4 a = row4[c];
            const float4 b = x4[c];
            sum += a.x * b.x + a.y * b.y + a.z * b.z + a.w * b.w;
        }
#pragma unroll
        for (int off = 32; off > 0; off >>= 1)
            sum += __shfl_down(sum, off, 64);
        __shared__ float red[4];
        const int lane = threadIdx.x & 63;
        if (lane == 0) red[threadIdx.x >> 6] = sum;
        __syncthreads();
        if (threadIdx.x == 0) {
            const float ssum = red[0] + red[1] + red[2] + red[3];
            out[o] = tanhf(ssum + b_h2o[o]);
        }
    }
}

extern "C" void kernel_launch(void* const* d_in, const int* in_sizes, int n_in,
                              void* d_out, int out_size, void* d_ws, size_t ws_size,
                              hipStream_t stream)
{
    const float* inp    = (const float*)d_in[0];
    const float* hidden = (const float*)d_in[1];
    const float* hebb   = (const float*)d_in[2];
    const float* W_i2h  = (const float*)d_in[3];
    const float* b_i2h  = (const float*)d_in[4];
    const float* w      = (const float*)d_in[5];
    const float* plas   = (const float*)d_in[6];
    const float* learn  = (const float*)d_in[7];
    const float* W_h2o  = (const float*)d_in[8];
    const float* b_h2o  = (const float*)d_in[9];

    float* out      = (float*)d_out;        // [64]
    float* x        = out + OUTN;           // [4096]
    float* hebb_out = x + H;                // [4096*4096]

    const size_t ctr_bytes  = 256;                                // aligned pad
    const size_t part_bytes = (size_t)SPLITS * H * sizeof(float); // 4 MB

    if (ws_size >= ctr_bytes + part_bytes) {
        unsigned* ctr  = (unsigned*)d_ws;
        float* partial = (float*)((char*)d_ws + ctr_bytes);
        // ctr region is poisoned 0xAA before every timed launch — zero it.
        hipMemsetAsync(ctr, 0, ctr_bytes, stream);
        fused_rnn<<<NBLK, 256, 0, stream>>>(inp, hidden, hebb, W_i2h, b_i2h,
                                            w, plas, learn, W_h2o, b_h2o,
                                            out, x, hebb_out, partial, ctr);
    } else {
        // fallback: proven 3-kernel path; partial aliases hebb_out start
        // (consumed by k_finish_x_fb before k_hebb_out_fb overwrites).
        const size_t fb_bytes = (size_t)FSPLITS * H * sizeof(float);
        float* partial = (ws_size >= fb_bytes) ? (float*)d_ws : hebb_out;
        k_partial_fb<<<dim3(4, FSPLITS), 256, 0, stream>>>(hidden, w, plas, hebb, partial);
        k_finish_x_fb<<<256, 256, 0, stream>>>(partial, inp, W_i2h, b_i2h, x);
        k_hebb_out_fb<<<H + OUTN, 256, 0, stream>>>(hebb, hidden, x, learn,
                                                    W_h2o, b_h2o, hebb_out, out);
    }
}